// Round 21
// baseline (170.846 us; speedup 1.0000x reference)
//
#include <hip/hip_runtime.h>

using i32x4  = __attribute__((ext_vector_type(4))) int;
using i32x16 = __attribute__((ext_vector_type(16))) int;

// ws layout (bytes); total = 43,458,560 B
#define OFF_SCALES 0u          // 512 f32
#define OFF_AB     4096u       // 1024 f32
#define OFF_PBUF   8192u       // 2 * 256ch * 896slots int32 = 1,835,008 B
#define OFF_WPK1   1843200u    // 589824 B int8
#define OFF_WPK2   2433024u    // 589824 B int8
#define OFF_SPAD   3022848u    // 64*30*30*256 int8 = 14,745,600 B (PRE-SWIZZLED)
#define OFF_COUT   17768448u   // 64*256*28*28 int16 = 25,690,112 B

__device__ __forceinline__ char sgn8(float v) {
  return v > 0.f ? (char)1 : (v < 0.f ? (char)-1 : (char)0);
}

// fused: pack sign(w) into 32x32x32-i8 MFMA A-fragment order + mean|w|.
// A layout: idx = khw*65536 + cc*8192 + mb*1024 + lane*16 + i with
// o = mb*32 + (lane&31), c = cc*32 + (lane>>5)*16 + i (mirrors B's map so
// the HW k-permutation cancels — refcheck'd in r20).
__global__ __launch_bounds__(256) void k_wprep2(const float* __restrict__ w1,
                                                const float* __restrict__ w2,
                                                char* __restrict__ wp1,
                                                char* __restrict__ wp2,
                                                float* __restrict__ sc) {
  int bid = blockIdx.x;
  int o = bid & 255, c = threadIdx.x;
  const float* w = (bid < 256) ? w1 : w2;
  char* wp = (bid < 256) ? wp1 : wp2;
  const float* wr = w + ((size_t)o * 256 + c) * 9;
  int lane = (o & 31) | (((c >> 4) & 1) << 5);
  int base = ((c >> 5) << 13) + ((o >> 5) << 10) + (lane << 4) + (c & 15);
  float s = 0.f;
#pragma unroll
  for (int khw = 0; khw < 9; ++khw) {
    float v = wr[khw];
    s += fabsf(v);
    wp[khw * 65536 + base] = sgn8(v);
  }
  for (int m = 1; m < 64; m <<= 1) s += __shfl_xor(s, m);
  __shared__ float red[4];
  if ((c & 63) == 0) red[c >> 6] = s;
  __syncthreads();
  if (c == 0) sc[bid] = (red[0] + red[1] + red[2] + red[3]) * (1.f / 2304.f);
}

// sign(x + b10) -> pre-swizzled padded NHWC int8 sign tensor [64][30][30][256].
// Granule g stored at slot g ^ ((28*rp + cp) & 15). Borders zeroed here.
__global__ __launch_bounds__(512) void k_e0(const float* __restrict__ x,
                                            const float* __restrict__ b10,
                                            char* __restrict__ sp) {
  __shared__ char lds[112 * 260];
  int img = blockIdx.x / 7, y4 = blockIdx.x % 7;
  int y0 = y4 * 4;
  int t = threadIdx.x;
  int r = t & 31;
  int cb = t >> 5;
  if (r < 28) {
    int p0 = r * 4;
    for (int ci = 0; ci < 16; ++ci) {
      int c = ci * 16 + cb;
      float vb = b10[c];
      size_t off = ((size_t)(img * 256 + c) * 28 + y0) * 28 + p0;
      float4 xv = *reinterpret_cast<const float4*>(x + off);
      char* lp = &lds[p0 * 260 + c];
      lp[0]   = sgn8(xv.x + vb);
      lp[260] = sgn8(xv.y + vb);
      lp[520] = sgn8(xv.z + vb);
      lp[780] = sgn8(xv.w + vb);
    }
  }
  __syncthreads();
#pragma unroll
  for (int row = 0; row < 4; ++row) {
    int rp = y0 + row + 1;
    size_t bse = (((size_t)img * 30 + rp) * 30 + 1) * 256;
    int* spi = (int*)(sp + bse);
    for (int q = t; q < 1792; q += 512) {
      int xo = q >> 6, ii = q & 63;
      int k = (28 * rp + xo + 1) & 15;
      int iw = (((ii >> 2) ^ k) << 2) | (ii & 3);
      spi[xo * 64 + iw] = *(const int*)&lds[(row * 28 + xo) * 260 + (ii << 2)];
    }
  }
  {
    int row = t >> 7, rem = t & 127;
    int col = (rem & 1) * 29, c4w = rem >> 1;
    ((int*)&sp[(((size_t)img * 30 + (y0 + row + 1)) * 30 + col) * 256])[c4w] = 0;
  }
  if (y4 == 0)
    for (int q = t; q < 1920; q += 512)
      ((int*)&sp[(size_t)img * 230400])[q] = 0;
  if (y4 == 6)
    for (int q = t; q < 1920; q += 512)
      ((int*)&sp[(size_t)img * 230400 + 29 * 7680])[q] = 0;
}

// binary conv via mfma_i32_32x32x32_i8 in the PROVEN envelope: block =
// 1 img x 4 output rows, 46KB LDS, 448 blocks (1.75-2 blocks/CU — r20's
// 92KB/1-block/224-grid starved the CU). 8 waves = 4 ch-groups x 2
// px-halves; wave = 64 out-ch (mi=2) x 64 px (2 j-tiles of 32; ph=1/j=1
// masks l31>=16). B ds_reads/block 2016 -> 1152 vs 16x16 shape.
// acc = 2x2 i32x16 = 64 regs -> fits the (512,4) 128-reg budget.
__global__ __launch_bounds__(512, 4) void k_conv(const char* __restrict__ S,
                                                 const char* __restrict__ Wp,
                                                 short* __restrict__ C,
                                                 int* __restrict__ P) {
  __shared__ char lds[46080];
  int bid = blockIdx.x;            // 448 = 64 img * 7 ytile
  int img = bid / 7, yt = bid % 7;
  int y0 = yt * 4;
  int tid = threadIdx.x;
  int wave = tid >> 6, lane = tid & 63;
  int l15 = lane & 15, l31 = lane & 31, lhi = lane >> 5;
  int chg = wave & 3, ph = wave >> 2;

  const char* sb = S + (size_t)img * 230400 + (size_t)y0 * 7680;
  for (int q = tid; q < 2880; q += 512) {
    __builtin_amdgcn_global_load_lds(
        (const __attribute__((address_space(1))) void*)(sb + (size_t)q * 16),
        (__attribute__((address_space(3))) void*)&lds[(q & ~63) * 16], 16, 0, 0);
  }
  __syncthreads();

  int pxb = ph * 64;
  int pixtp[2];
#pragma unroll
  for (int j = 0; j < 2; ++j) {
    int p = pxb + j * 32 + l31;
    int pc = p < 112 ? p : 111;
    pixtp[j] = (pc / 28) * 30 + (pc % 28);
  }
  i32x16 acc[2][2] = {};
  int ybias = (12 * y0) & 15;

#pragma unroll 1
  for (int kh = 0; kh < 3; ++kh) {
#pragma unroll
    for (int kw = 0; kw < 3; ++kw) {
      int shift = kh * 30 + kw;
      int kk = (ybias + l15 + 12 * kh + kw) & 15;
      const char* ab = Wp + (size_t)(kh * 3 + kw) * 65536 + chg * 2048 + lane * 16;
#pragma unroll
      for (int cc = 0; cc < 8; ++cc) {
        i32x4 afr0 = *reinterpret_cast<const i32x4*>(ab + cc * 8192);
        i32x4 afr1 = *reinterpret_cast<const i32x4*>(ab + cc * 8192 + 1024);
        int gr = (cc * 2 + lhi) ^ kk;
        i32x4 bfr[2];
#pragma unroll
        for (int j = 0; j < 2; ++j)
          bfr[j] = *reinterpret_cast<const i32x4*>(&lds[(pixtp[j] + shift) * 256 + (gr << 4)]);
#pragma unroll
        for (int j = 0; j < 2; ++j) {
          acc[0][j] = __builtin_amdgcn_mfma_i32_32x32x32_i8(afr0, bfr[j], acc[0][j], 0, 0, 0);
          acc[1][j] = __builtin_amdgcn_mfma_i32_32x32x32_i8(afr1, bfr[j], acc[1][j], 0, 0, 0);
        }
      }
    }
  }

  // C/D: col = lane&31 (px), row = (reg&3) + 8*(reg>>2) + 4*(lane>>5)
  short* cb = C + (size_t)img * 200704;
#pragma unroll
  for (int mi = 0; mi < 2; ++mi) {
#pragma unroll
    for (int reg = 0; reg < 16; ++reg) {
      int o = chg * 64 + mi * 32 + (reg & 3) + ((reg >> 2) << 3) + (lhi << 2);
      int s1 = 0, s2 = 0;
#pragma unroll
      for (int j = 0; j < 2; ++j) {
        int px = pxb + j * 32 + l31;
        if (px < 112) {
          int v = acc[mi][j][reg];
          cb[(size_t)o * 784 + (y0 + px / 28) * 28 + (px % 28)] = (short)v;
          s1 += v;
          s2 += v * v;
        }
      }
#pragma unroll
      for (int m = 1; m < 32; m <<= 1) {
        s1 += __shfl_xor(s1, m);
        s2 += __shfl_xor(s2, m);
      }
      if (l31 == 0) {
        P[o * 896 + bid * 2 + ph] = s1;
        P[229376 + o * 896 + bid * 2 + ph] = s2;
      }
    }
  }
}

// reduce 896 per-(block,ph) partials per channel + fused bnprep -> AB.
__global__ __launch_bounds__(256) void k_stats2(const int* __restrict__ P,
                                                const float* __restrict__ scale,
                                                const float* __restrict__ gamma,
                                                const float* __restrict__ beta,
                                                float* __restrict__ AB) {
  int o = blockIdx.x, t = threadIdx.x;
  long long s1 = 0, s2 = 0;
  for (int q = t; q < 896; q += 256) {
    s1 += P[o * 896 + q];
    s2 += P[229376 + o * 896 + q];
  }
  for (int m = 1; m < 64; m <<= 1) {
    s1 += __shfl_xor(s1, m);
    s2 += __shfl_xor(s2, m);
  }
  __shared__ long long rs1[4], rs2[4];
  if ((t & 63) == 0) { rs1[t >> 6] = s1; rs2[t >> 6] = s2; }
  __syncthreads();
  if (t == 0) {
    long long S1 = rs1[0] + rs1[1] + rs1[2] + rs1[3];
    long long S2 = rs2[0] + rs2[1] + rs2[2] + rs2[3];
    double n  = 50176.0;
    double sc = (double)scale[o];
    double mI = (double)S1 / n;
    double vI = (double)S2 / n - mI * mI;
    double mu  = sc * mI;
    double var = sc * sc * vI;
    double rr = 1.0 / sqrt(var + 1e-5);
    double g = (double)gamma[o];
    AB[o]       = (float)(g * sc * rr);
    AB[256 + o] = (float)((double)beta[o] - g * rr * mu);
  }
}

// h = prelu(bn1(c1) + x + b11, a1) + b12 -> d_out; sign(h+b20) -> spad
// (pre-swizzled). Vectorized float4/short4.
__global__ __launch_bounds__(512) void k_e1(const short* __restrict__ c1,
                                            const float* __restrict__ x,
                                            const float* __restrict__ AB,
                                            const float* __restrict__ b11,
                                            const float* __restrict__ a1,
                                            const float* __restrict__ b12,
                                            const float* __restrict__ b20,
                                            float* __restrict__ ho,
                                            char* __restrict__ sp) {
  __shared__ char lds[112 * 260];
  int img = blockIdx.x / 7, y4 = blockIdx.x % 7;
  int y0 = y4 * 4;
  int t = threadIdx.x;
  int r = t & 31;
  int cb = t >> 5;
  if (r < 28) {
    int p0 = r * 4;
    for (int ci = 0; ci < 16; ++ci) {
      int c = ci * 16 + cb;
      float A = AB[c], B = AB[256 + c];
      float v11 = b11[c], va = a1[c], v12 = b12[c], v20 = b20[c];
      size_t off = ((size_t)(img * 256 + c) * 28 + y0) * 28 + p0;
      float4 xv = *reinterpret_cast<const float4*>(x + off);
      short4 cv = *reinterpret_cast<const short4*>(c1 + off);
      float h0 = A * (float)cv.x + B + xv.x + v11; h0 = h0 >= 0.f ? h0 : va * h0; h0 += v12;
      float h1 = A * (float)cv.y + B + xv.y + v11; h1 = h1 >= 0.f ? h1 : va * h1; h1 += v12;
      float h2 = A * (float)cv.z + B + xv.z + v11; h2 = h2 >= 0.f ? h2 : va * h2; h2 += v12;
      float h3 = A * (float)cv.w + B + xv.w + v11; h3 = h3 >= 0.f ? h3 : va * h3; h3 += v12;
      float4 hv; hv.x = h0; hv.y = h1; hv.z = h2; hv.w = h3;
      *reinterpret_cast<float4*>(ho + off) = hv;
      char* lp = &lds[p0 * 260 + c];
      lp[0]   = sgn8(h0 + v20);
      lp[260] = sgn8(h1 + v20);
      lp[520] = sgn8(h2 + v20);
      lp[780] = sgn8(h3 + v20);
    }
  }
  __syncthreads();
#pragma unroll
  for (int row = 0; row < 4; ++row) {
    int rp = y0 + row + 1;
    size_t bse = (((size_t)img * 30 + rp) * 30 + 1) * 256;
    int* spi = (int*)(sp + bse);
    for (int q = t; q < 1792; q += 512) {
      int xo = q >> 6, ii = q & 63;
      int k = (28 * rp + xo + 1) & 15;
      int iw = (((ii >> 2) ^ k) << 2) | (ii & 3);
      spi[xo * 64 + iw] = *(const int*)&lds[(row * 28 + xo) * 260 + (ii << 2)];
    }
  }
  // borders already zero from k_e0
}

// y = prelu(bn2(c2) + h + b21, a2) + b22, in place on d_out (h)
__global__ __launch_bounds__(256) void k_e2(const short* __restrict__ c2,
                                            const float* __restrict__ AB2,
                                            const float* __restrict__ b21,
                                            const float* __restrict__ a2,
                                            const float* __restrict__ b22,
                                            float* __restrict__ io) {
  int v = blockIdx.x * 256 + threadIdx.x;  // < 3211264 float4s
  int c = ((v * 4) / 784) & 255;
  float A = AB2[c], B = AB2[256 + c];
  float p21 = b21[c], aa = a2[c], p22 = b22[c];
  short4 I = reinterpret_cast<const short4*>(c2)[v];
  float4 h = reinterpret_cast<const float4*>(io)[v];
  float4 r;
  float t0 = A * (float)I.x + B + h.x + p21; t0 = t0 >= 0.f ? t0 : aa * t0; r.x = t0 + p22;
  float t1 = A * (float)I.y + B + h.y + p21; t1 = t1 >= 0.f ? t1 : aa * t1; r.y = t1 + p22;
  float t2 = A * (float)I.z + B + h.z + p21; t2 = t2 >= 0.f ? t2 : aa * t2; r.z = t2 + p22;
  float t3 = A * (float)I.w + B + h.w + p21; t3 = t3 >= 0.f ? t3 : aa * t3; r.w = t3 + p22;
  reinterpret_cast<float4*>(io)[v] = r;
}

extern "C" void kernel_launch(void* const* d_in, const int* in_sizes, int n_in,
                              void* d_out, int out_size, void* d_ws, size_t ws_size,
                              hipStream_t stream) {
  const float* x      = (const float*)d_in[0];
  const float* b10    = (const float*)d_in[1];
  const float* w1     = (const float*)d_in[2];
  const float* gamma1 = (const float*)d_in[3];
  const float* beta1  = (const float*)d_in[4];
  const float* b11    = (const float*)d_in[5];
  const float* a1     = (const float*)d_in[6];
  const float* b12    = (const float*)d_in[7];
  const float* b20    = (const float*)d_in[8];
  const float* w2     = (const float*)d_in[9];
  const float* gamma2 = (const float*)d_in[10];
  const float* beta2  = (const float*)d_in[11];
  const float* b21    = (const float*)d_in[12];
  const float* a2     = (const float*)d_in[13];
  const float* b22    = (const float*)d_in[14];
  float* out = (float*)d_out;

  char* ws = (char*)d_ws;
  float* scales = (float*)(ws + OFF_SCALES);
  float* AB     = (float*)(ws + OFF_AB);
  int*   pbuf   = (int*)(ws + OFF_PBUF);
  char*  wpk1   = ws + OFF_WPK1;
  char*  wpk2   = ws + OFF_WPK2;
  char*  spad   = ws + OFF_SPAD;
  short* cout   = (short*)(ws + OFF_COUT);

  k_wprep2<<<512, 256, 0, stream>>>(w1, w2, wpk1, wpk2, scales);

  k_e0<<<448, 512, 0, stream>>>(x, b10, spad);
  k_conv<<<448, 512, 0, stream>>>(spad, wpk1, cout, pbuf);
  k_stats2<<<256, 256, 0, stream>>>(pbuf, scales, gamma1, beta1, AB);
  k_e1<<<448, 512, 0, stream>>>(cout, x, AB, b11, a1, b12, b20, out, spad);
  k_conv<<<448, 512, 0, stream>>>(spad, wpk2, cout, pbuf);
  k_stats2<<<256, 256, 0, stream>>>(pbuf, scales + 256, gamma2, beta2, AB + 512);
  k_e2<<<12544, 256, 0, stream>>>(cout, AB + 512, b21, a2, b22, out);
}

// Round 22
// 132.602 us; speedup vs baseline: 1.2884x; 1.2884x over previous
//
#include <hip/hip_runtime.h>

using i32x4 = __attribute__((ext_vector_type(4))) int;

// ws layout (bytes); total = 42,541,056 B
#define OFF_SCALES 0u          // 512 f32
#define OFF_AB     4096u       // 1024 f32
#define OFF_PBUF   8192u       // 2 * 256ch * 448blk int32 = 917,504 B
#define OFF_WPK1   925696u     // 589824 B int8
#define OFF_WPK2   1515520u    // 589824 B int8
#define OFF_SPAD   2105344u    // 64*30*30*256 int8 = 14,745,600 B
#define OFF_COUT   16850944u   // 64*256*28*28 int16 = 25,690,112 B

__device__ __forceinline__ char sgn8(float v) {
  return v > 0.f ? (char)1 : (v < 0.f ? (char)-1 : (char)0);
}

// fused: pack sign(w) into i8-MFMA A-fragment order AND per-filter mean|w|.
// 512 blocks: bid<256 -> w1/wpk1/scales[0..255], else w2/wpk2/scales[256..].
__global__ __launch_bounds__(256) void k_wprep2(const float* __restrict__ w1,
                                                const float* __restrict__ w2,
                                                char* __restrict__ wp1,
                                                char* __restrict__ wp2,
                                                float* __restrict__ sc) {
  int bid = blockIdx.x;
  int o = bid & 255, c = threadIdx.x;
  const float* w = (bid < 256) ? w1 : w2;
  char* wp = (bid < 256) ? wp1 : wp2;
  const float* wr = w + ((size_t)o * 256 + c) * 9;
  int base = ((c >> 6) * 16384) + ((o >> 4) * 1024) +
             (((o & 15) + (((c >> 4) & 3) << 4)) << 4) + (c & 15);
  float s = 0.f;
#pragma unroll
  for (int khw = 0; khw < 9; ++khw) {
    float v = wr[khw];
    s += fabsf(v);
    wp[khw * 65536 + base] = sgn8(v);
  }
  for (int m = 1; m < 64; m <<= 1) s += __shfl_xor(s, m);
  __shared__ float red[4];
  if ((c & 63) == 0) red[c >> 6] = s;
  __syncthreads();
  if (c == 0) sc[bid] = (red[0] + red[1] + red[2] + red[3]) * (1.f / 2304.f);
}

// sign(x + b10) -> padded NHWC int8 sign tensor [64][30][30][256].
// Vectorized: block = (img, 4-row slab), float4 x reads, px-major LDS
// transpose, 256B/px coalesced spad writes. Also zeroes the pad border.
__global__ __launch_bounds__(512) void k_e0(const float* __restrict__ x,
                                            const float* __restrict__ b10,
                                            char* __restrict__ sp) {
  __shared__ char lds[112 * 260];
  int img = blockIdx.x / 7, y4 = blockIdx.x % 7;
  int y0 = y4 * 4;
  int t = threadIdx.x;
  int r = t & 31;
  int cb = t >> 5;
  if (r < 28) {
    int p0 = r * 4;
    for (int ci = 0; ci < 16; ++ci) {
      int c = ci * 16 + cb;
      float vb = b10[c];
      size_t off = ((size_t)(img * 256 + c) * 28 + y0) * 28 + p0;
      float4 xv = *reinterpret_cast<const float4*>(x + off);
      char* lp = &lds[p0 * 260 + c];
      lp[0]   = sgn8(xv.x + vb);
      lp[260] = sgn8(xv.y + vb);
      lp[520] = sgn8(xv.z + vb);
      lp[780] = sgn8(xv.w + vb);
    }
  }
  __syncthreads();
#pragma unroll
  for (int row = 0; row < 4; ++row) {
    size_t bse = (((size_t)img * 30 + (y0 + row + 1)) * 30 + 1) * 256;
    int* spi = (int*)(sp + bse);
    for (int q = t; q < 1792; q += 512) {
      int xo = q >> 6, c4 = (q & 63) << 2;
      spi[q] = *(const int*)&lds[(row * 28 + xo) * 260 + c4];
    }
  }
  {
    int row = t >> 7, rem = t & 127;
    int col = (rem & 1) * 29, c4w = rem >> 1;
    ((int*)&sp[(((size_t)img * 30 + (y0 + row + 1)) * 30 + col) * 256])[c4w] = 0;
  }
  if (y4 == 0)
    for (int q = t; q < 1920; q += 512)
      ((int*)&sp[(size_t)img * 230400])[q] = 0;
  if (y4 == 6)
    for (int q = t; q < 1920; q += 512)
      ((int*)&sp[(size_t)img * 230400 + 29 * 7680])[q] = 0;
}

// binary conv as implicit GEMM with i8 MFMA (exact int32 counts).
// Round-9 body (VGPR 64-72, spill-free). Epilogue: per-block partial sums
// (s1,s2 int32 — 112*2304^2 = 5.9e8 < 2^31) to dedicated non-atomic slots
// P[o*448+bid] / P[114688+o*448+bid]. (Atomics were a ~50us serialized
// tail — round 16; partials keep stats info without the cout re-read.)
__global__ __launch_bounds__(512, 4) void k_conv(const char* __restrict__ S,
                                                 const char* __restrict__ Wp,
                                                 short* __restrict__ C,
                                                 int* __restrict__ P) {
  __shared__ char lds[46080];
  int bid = blockIdx.x;            // 448 = 64 img * 7 ytile
  int img = bid / 7;
  int yt  = bid % 7;
  int tid = threadIdx.x;
  int wave = tid >> 6, lane = tid & 63;
  int l15 = lane & 15, lg = lane >> 4;
  int y0 = yt * 4;

  const char* sb = S + (size_t)img * 230400 + (size_t)y0 * 7680;
  for (int q = tid; q < 2880; q += 512) {
    int tp = q >> 4;
    int g  = q & 15;
    int k  = (tp - 2 * (tp / 30)) & 15;   // == (28*row + col) & 15
    int4 v = *reinterpret_cast<const int4*>(sb + tp * 256 + g * 16);
    *reinterpret_cast<int4*>(&lds[tp * 256 + ((g ^ k) << 4)]) = v;
  }
  __syncthreads();

  int pixtp[7];
#pragma unroll
  for (int j = 0; j < 7; ++j) {
    int p = j * 16 + l15;
    pixtp[j] = (p / 28) * 30 + (p % 28);
  }
  i32x4 acc[2][7] = {};

#pragma unroll 1
  for (int kh = 0; kh < 3; ++kh) {
#pragma unroll
    for (int kw = 0; kw < 3; ++kw) {
      int khw = kh * 3 + kw;
      int shift = kh * 30 + kw;
      int kk = (l15 + 12 * kh + kw) & 15;
      const char* ab = Wp + (size_t)khw * 65536 + (size_t)wave * 2048 + lane * 16;
#pragma unroll
      for (int cc = 0; cc < 4; ++cc) {
        i32x4 afr[2];
        afr[0] = *reinterpret_cast<const i32x4*>(ab + cc * 16384);
        afr[1] = *reinterpret_cast<const i32x4*>(ab + cc * 16384 + 1024);
        int gr = (lg + 4 * cc) ^ kk;
        i32x4 bfr[7];
#pragma unroll
        for (int j = 0; j < 7; ++j) {
          int tp = pixtp[j] + shift;
          bfr[j] = *reinterpret_cast<const i32x4*>(&lds[tp * 256 + (gr << 4)]);
        }
#pragma unroll
        for (int mi = 0; mi < 2; ++mi)
#pragma unroll
          for (int j = 0; j < 7; ++j)
            acc[mi][j] = __builtin_amdgcn_mfma_i32_16x16x64_i8(afr[mi], bfr[j], acc[mi][j], 0, 0, 0);
      }
    }
  }

  short* cb = C + (size_t)img * 200704;
#pragma unroll
  for (int mi = 0; mi < 2; ++mi) {
#pragma unroll
    for (int r = 0; r < 4; ++r) {
      int o = wave * 32 + mi * 16 + lg * 4 + r;
      int s1 = 0, s2 = 0;
#pragma unroll
      for (int j = 0; j < 7; ++j) {
        int iv = acc[mi][j][r];
        int p = j * 16 + l15;
        cb[(size_t)o * 784 + (y0 + p / 28) * 28 + (p % 28)] = (short)iv;
        s1 += iv;
        s2 += iv * iv;
      }
#pragma unroll
      for (int m = 1; m < 16; m <<= 1) {
        s1 += __shfl_xor(s1, m);
        s2 += __shfl_xor(s2, m);
      }
      if (l15 == 0) {
        P[o * 448 + bid] = s1;
        P[114688 + o * 448 + bid] = s2;
      }
    }
  }
}

// reduce 448 per-block partials per channel + fused bnprep -> AB affine.
__global__ __launch_bounds__(256) void k_stats2(const int* __restrict__ P,
                                                const float* __restrict__ scale,
                                                const float* __restrict__ gamma,
                                                const float* __restrict__ beta,
                                                float* __restrict__ AB) {
  int o = blockIdx.x, t = threadIdx.x;
  long long s1 = 0, s2 = 0;
  for (int q = t; q < 448; q += 256) {
    s1 += P[o * 448 + q];
    s2 += P[114688 + o * 448 + q];
  }
  for (int m = 1; m < 64; m <<= 1) {
    s1 += __shfl_xor(s1, m);
    s2 += __shfl_xor(s2, m);
  }
  __shared__ long long rs1[4], rs2[4];
  if ((t & 63) == 0) { rs1[t >> 6] = s1; rs2[t >> 6] = s2; }
  __syncthreads();
  if (t == 0) {
    long long S1 = rs1[0] + rs1[1] + rs1[2] + rs1[3];
    long long S2 = rs2[0] + rs2[1] + rs2[2] + rs2[3];
    double n  = 50176.0;
    double sc = (double)scale[o];
    double mI = (double)S1 / n;
    double vI = (double)S2 / n - mI * mI;
    double mu  = sc * mI;
    double var = sc * sc * vI;
    double rr = 1.0 / sqrt(var + 1e-5);
    double g = (double)gamma[o];
    AB[o]       = (float)(g * sc * rr);
    AB[256 + o] = (float)((double)beta[o] - g * rr * mu);
  }
}

// h = prelu(bn1(c1) + x + b11, a1) + b12 -> d_out; sign(h+b20) -> spad.
// Vectorized: float4 x + short4 c1 + float4 ho per thread.
__global__ __launch_bounds__(512) void k_e1(const short* __restrict__ c1,
                                            const float* __restrict__ x,
                                            const float* __restrict__ AB,
                                            const float* __restrict__ b11,
                                            const float* __restrict__ a1,
                                            const float* __restrict__ b12,
                                            const float* __restrict__ b20,
                                            float* __restrict__ ho,
                                            char* __restrict__ sp) {
  __shared__ char lds[112 * 260];
  int img = blockIdx.x / 7, y4 = blockIdx.x % 7;
  int y0 = y4 * 4;
  int t = threadIdx.x;
  int r = t & 31;
  int cb = t >> 5;
  if (r < 28) {
    int p0 = r * 4;
    for (int ci = 0; ci < 16; ++ci) {
      int c = ci * 16 + cb;
      float A = AB[c], B = AB[256 + c];
      float v11 = b11[c], va = a1[c], v12 = b12[c], v20 = b20[c];
      size_t off = ((size_t)(img * 256 + c) * 28 + y0) * 28 + p0;
      float4 xv = *reinterpret_cast<const float4*>(x + off);
      short4 cv = *reinterpret_cast<const short4*>(c1 + off);
      float h0 = A * (float)cv.x + B + xv.x + v11; h0 = h0 >= 0.f ? h0 : va * h0; h0 += v12;
      float h1 = A * (float)cv.y + B + xv.y + v11; h1 = h1 >= 0.f ? h1 : va * h1; h1 += v12;
      float h2 = A * (float)cv.z + B + xv.z + v11; h2 = h2 >= 0.f ? h2 : va * h2; h2 += v12;
      float h3 = A * (float)cv.w + B + xv.w + v11; h3 = h3 >= 0.f ? h3 : va * h3; h3 += v12;
      float4 hv; hv.x = h0; hv.y = h1; hv.z = h2; hv.w = h3;
      *reinterpret_cast<float4*>(ho + off) = hv;
      char* lp = &lds[p0 * 260 + c];
      lp[0]   = sgn8(h0 + v20);
      lp[260] = sgn8(h1 + v20);
      lp[520] = sgn8(h2 + v20);
      lp[780] = sgn8(h3 + v20);
    }
  }
  __syncthreads();
#pragma unroll
  for (int row = 0; row < 4; ++row) {
    size_t bse = (((size_t)img * 30 + (y0 + row + 1)) * 30 + 1) * 256;
    int* spi = (int*)(sp + bse);
    for (int q = t; q < 1792; q += 512) {
      int xo = q >> 6, c4 = (q & 63) << 2;
      spi[q] = *(const int*)&lds[(row * 28 + xo) * 260 + c4];
    }
  }
  // borders already zero from k_e0
}

// y = prelu(bn2(c2) + h + b21, a2) + b22, in place on d_out (h)
__global__ __launch_bounds__(256) void k_e2(const short* __restrict__ c2,
                                            const float* __restrict__ AB2,
                                            const float* __restrict__ b21,
                                            const float* __restrict__ a2,
                                            const float* __restrict__ b22,
                                            float* __restrict__ io) {
  int v = blockIdx.x * 256 + threadIdx.x;  // < 3211264 float4s
  int c = ((v * 4) / 784) & 255;
  float A = AB2[c], B = AB2[256 + c];
  float p21 = b21[c], aa = a2[c], p22 = b22[c];
  short4 I = reinterpret_cast<const short4*>(c2)[v];
  float4 h = reinterpret_cast<const float4*>(io)[v];
  float4 r;
  float t0 = A * (float)I.x + B + h.x + p21; t0 = t0 >= 0.f ? t0 : aa * t0; r.x = t0 + p22;
  float t1 = A * (float)I.y + B + h.y + p21; t1 = t1 >= 0.f ? t1 : aa * t1; r.y = t1 + p22;
  float t2 = A * (float)I.z + B + h.z + p21; t2 = t2 >= 0.f ? t2 : aa * t2; r.z = t2 + p22;
  float t3 = A * (float)I.w + B + h.w + p21; t3 = t3 >= 0.f ? t3 : aa * t3; r.w = t3 + p22;
  reinterpret_cast<float4*>(io)[v] = r;
}

extern "C" void kernel_launch(void* const* d_in, const int* in_sizes, int n_in,
                              void* d_out, int out_size, void* d_ws, size_t ws_size,
                              hipStream_t stream) {
  const float* x      = (const float*)d_in[0];
  const float* b10    = (const float*)d_in[1];
  const float* w1     = (const float*)d_in[2];
  const float* gamma1 = (const float*)d_in[3];
  const float* beta1  = (const float*)d_in[4];
  const float* b11    = (const float*)d_in[5];
  const float* a1     = (const float*)d_in[6];
  const float* b12    = (const float*)d_in[7];
  const float* b20    = (const float*)d_in[8];
  const float* w2     = (const float*)d_in[9];
  const float* gamma2 = (const float*)d_in[10];
  const float* beta2  = (const float*)d_in[11];
  const float* b21    = (const float*)d_in[12];
  const float* a2     = (const float*)d_in[13];
  const float* b22    = (const float*)d_in[14];
  float* out = (float*)d_out;

  char* ws = (char*)d_ws;
  float* scales = (float*)(ws + OFF_SCALES);
  float* AB     = (float*)(ws + OFF_AB);
  int*   pbuf   = (int*)(ws + OFF_PBUF);
  char*  wpk1   = ws + OFF_WPK1;
  char*  wpk2   = ws + OFF_WPK2;
  char*  spad   = ws + OFF_SPAD;
  short* cout   = (short*)(ws + OFF_COUT);

  k_wprep2<<<512, 256, 0, stream>>>(w1, w2, wpk1, wpk2, scales);

  k_e0<<<448, 512, 0, stream>>>(x, b10, spad);
  k_conv<<<448, 512, 0, stream>>>(spad, wpk1, cout, pbuf);
  k_stats2<<<256, 256, 0, stream>>>(pbuf, scales, gamma1, beta1, AB);
  k_e1<<<448, 512, 0, stream>>>(cout, x, AB, b11, a1, b12, b20, out, spad);
  k_conv<<<448, 512, 0, stream>>>(spad, wpk2, cout, pbuf);
  k_stats2<<<256, 256, 0, stream>>>(pbuf, scales + 256, gamma2, beta2, AB + 512);
  k_e2<<<12544, 256, 0, stream>>>(cout, AB + 512, b21, a2, b22, out);
}